// Round 9
// baseline (15464.586 us; speedup 1.0000x reference)
//
#include <hip/hip_runtime.h>
#include <cmath>

#define B 128
#define T 128
#define H 512
#define TGT 32
#define SCOPE_AGENT __HIP_MEMORY_SCOPE_AGENT

// ws: dst [4][B][H] f32 (1MB) | ctr 16KB | l0/G1 [T][B][1024] f32 (64MB)
struct Args {
  const float *x, *eWih0, *eWhh0, *eWih1, *eWhh1, *ebih, *ebhh;
  const float *dWih0, *dWihr, *dWhh, *dbih, *dbhh, *linW, *linb;
  float *dst; float *l0; unsigned *ctr; float *out;
};

__global__ void kinit(unsigned* __restrict__ ctr) {
  int idx = blockIdx.x * 256 + threadIdx.x;
  if (idx < 4096) ctr[idx] = 0u;
}

__device__ __forceinline__ float d4(float4 a, float4 b) {
  return a.x * b.x + a.y * b.y + a.z * b.z + a.w * b.w;
}
// phase barrier (acq/rel) — only 3 uses, proven in rounds 4/6/7
__device__ __forceinline__ void gridbar(unsigned* g, unsigned tgt) {
  __syncthreads();
  if (threadIdx.x == 0) {
    __hip_atomic_fetch_add(g, 1u, __ATOMIC_RELEASE, SCOPE_AGENT);
    while (__hip_atomic_load(g, __ATOMIC_RELAXED, SCOPE_AGENT) < tgt)
      __builtin_amdgcn_s_sleep(1);
    (void)__hip_atomic_load(g, __ATOMIC_ACQUIRE, SCOPE_AGENT);
  }
  __syncthreads();
}

// ===========================================================================
// Encoder (E0 / E1): 64 active blocks, each owns 4 whole chains (dir, b0..b0+3).
// No inter-block traffic. Thread (n2, kh): rows {n2, n2+256}, K-half kh.
// h ping-pong in LDS (broadcast reads); W streamed from L2 each step.
// ===========================================================================
template <bool E0P>
__device__ void enc_phase(const Args& a, float* sm, int bx, int tid) {
  if (bx >= 64) return;
  const int dir = bx >> 5, b0 = (bx & 31) * 4;
  const int n2 = tid & 255, kh = tid >> 8;
  const float* WHH = E0P ? a.eWhh0 : a.eWhh1;
  const float* WrA = WHH + (size_t)(dir * H + n2) * H + kh * 256;
  const float* WrB = WHH + (size_t)(dir * H + n2 + 256) * H + kh * 256;
  float* HC = sm;          // [4][512]
  float* HN = sm + 2048;   // [4][512]
  float* PT = sm + 4096;   // [16][256]
  float* XS = sm + 8192;   // [4][384] (E0 only)

  for (int i = tid; i < 2048; i += 512) HC[i] = 0.f;
  float bias = 0.f, wx0 = 0.f, wx1 = 0.f, wx2 = 0.f;
  if (E0P) {
    for (int i = tid; i < 1536; i += 512) {
      int m = i / 384, r = i - m * 384;
      XS[i] = a.x[(size_t)(b0 + m) * 384 + r];
    }
    bias = a.ebih[dir * H + tid] + a.ebhh[dir * H + tid];
    wx0 = a.eWih0[(dir * H + tid) * 3 + 0];
    wx1 = a.eWih0[(dir * H + tid) * 3 + 1];
    wx2 = a.eWih0[(dir * H + tid) * 3 + 2];
  }
  __syncthreads();

  float* hc = HC; float* hn = HN;
  for (int s = 0; s < T; s++) {
    const int t = dir ? (T - 1 - s) : s;
    float a0[4] = {0.f, 0.f, 0.f, 0.f}, a1[4] = {0.f, 0.f, 0.f, 0.f};
    const float* hk = hc + kh * 256;
#pragma unroll 4
    for (int kk = 0; kk < 256; kk += 4) {
      float4 wa = *(const float4*)(WrA + kk);
      float4 wb = *(const float4*)(WrB + kk);
#pragma unroll
      for (int m = 0; m < 4; m++) {
        float4 h4 = *(const float4*)(hk + m * 512 + kk);   // broadcast
        a0[m] += d4(wa, h4);
        a1[m] += d4(wb, h4);
      }
    }
#pragma unroll
    for (int m = 0; m < 4; m++) {
      PT[((kh * 2 + 0) * 4 + m) * 256 + n2] = a0[m];
      PT[((kh * 2 + 1) * 4 + m) * 256 + n2] = a1[m];
    }
    __syncthreads();
    {
      const int j = tid >> 8, nn2 = tid & 255;   // output n = tid
      float g1v[4];
      if (!E0P) {
#pragma unroll
        for (int m = 0; m < 4; m++)
          g1v[m] = a.l0[((size_t)t * B + b0 + m) * 1024 + dir * 512 + tid];
      }
#pragma unroll
      for (int m = 0; m < 4; m++) {
        float sum = PT[((0 * 2 + j) * 4 + m) * 256 + nn2]
                  + PT[((1 * 2 + j) * 4 + m) * 256 + nn2];
        float pre;
        if (E0P) {
          const float* xr = XS + m * 384 + t * 3;
          pre = sum + bias + xr[0] * wx0 + xr[1] * wx1 + xr[2] * wx2;
        } else {
          pre = sum + g1v[m];   // G1 already holds proj + biases
        }
        float o = tanhf(pre);
        hn[m * 512 + tid] = o;
        if (E0P) a.l0[((size_t)t * B + b0 + m) * 1024 + dir * 512 + tid] = o;
        if (s == T - 1)
          a.dst[(size_t)((E0P ? 0 : 2) + dir) * B * H + (size_t)(b0 + m) * H + tid] = o;
      }
    }
    __syncthreads();
    float* tmp = hc; hc = hn; hn = tmp;
  }
}

// ===========================================================================
// enc1 input projection, in-place over l0 (adds layer-1 biases).
// 128 blocks x 8 row-groups of 16 => all 16384 rows covered (round-8 bug fix:
// bx*16 with 128 blocks only covered 2048 rows). x-slab LDS-resident before
// in-place overwrite (block-local rows only); W streamed from L2 per group.
// ===========================================================================
__device__ void proj_phase(const Args& a, float* sm, int bx, int tid) {
  const int c = tid;
  const float* W0 = a.eWih1 + (size_t)c * 1024;
  const float* W1 = a.eWih1 + (size_t)(c + 512) * 1024;
  const float ba = a.ebih[1024 + c] + a.ebhh[1024 + c];
  const float bb = a.ebih[1024 + c + 512] + a.ebhh[1024 + c + 512];
  for (int it = 0; it < 8; it++) {
    const int r0 = bx * 128 + it * 16;
    __syncthreads();                       // sm free (prev iter writes done)
    for (int i = tid; i < 4096; i += 512) {          // 16 rows x 256 float4
      int r = i >> 8, seg = i & 255;
      *(float4*)(sm + r * 1032 + seg * 4) =
          *(const float4*)(a.l0 + (size_t)(r0 + r) * 1024 + seg * 4);
    }
    __syncthreads();
    float acc0[16], acc1[16];
#pragma unroll
    for (int r = 0; r < 16; r++) { acc0[r] = 0.f; acc1[r] = 0.f; }
#pragma unroll 2
    for (int kk = 0; kk < 1024; kk += 4) {
      float4 wa = *(const float4*)(W0 + kk);
      float4 wb = *(const float4*)(W1 + kk);
#pragma unroll
      for (int r = 0; r < 16; r++) {
        float4 xv = *(const float4*)(sm + r * 1032 + kk);   // broadcast
        acc0[r] += d4(wa, xv);
        acc1[r] += d4(wb, xv);
      }
    }
    __syncthreads();   // all x-slab reads complete before in-place writes
    for (int r = 0; r < 16; r++) {
      a.l0[(size_t)(r0 + r) * 1024 + c] = acc0[r] + ba;
      a.l0[(size_t)(r0 + r) * 1024 + c + 512] = acc1[r] + bb;
    }
  }
}

// ===========================================================================
// Decoder: 32 active blocks, each owns 4 whole chains (b0..b0+3): full 4-layer
// stack + head + xin feedback in-block. Zero inter-block traffic.
// ===========================================================================
__device__ void dec_phase(const Args& a, float* sm, int bx, int tid) {
  if (bx >= 32) return;
  const int b0 = bx * 4;
  const int n = tid;
  float* Hs  = sm;           // [4 l][4 m][512] = 8192
  float* P2  = sm + 8192;    // [4][136]
  float* XIN = sm + 8752;    // [4][4]

  for (int i = tid; i < 2048; i += 512) {          // 16 rows x 128 float4
    int row = i >> 7, seg = i & 127;
    int l = row >> 2, m = row & 3;
    *(float4*)(Hs + row * 512 + seg * 4) =
        *(const float4*)(a.dst + ((size_t)l * B + b0 + m) * H + seg * 4);
  }
  if (tid < 4) {
    const float* xr = a.x + (size_t)(b0 + tid) * 384 + 381;
    XIN[tid * 4 + 0] = xr[0]; XIN[tid * 4 + 1] = xr[1];
    XIN[tid * 4 + 2] = xr[2]; XIN[tid * 4 + 3] = 0.f;
  }
  float biasl[4];
#pragma unroll
  for (int l = 0; l < 4; l++) biasl[l] = a.dbih[l * H + n] + a.dbhh[l * H + n];
  float wxd0 = a.dWih0[n * 3 + 0];
  float wxd1 = a.dWih0[n * 3 + 1];
  float wxd2 = a.dWih0[n * 3 + 2];
  float4 lw = *(const float4*)(a.linW + (tid & 127) * 4);
  float lb = a.linb[0];
  __syncthreads();

  for (int s = 0; s < TGT; s++) {
    for (int l = 0; l < 4; l++) {
      float acc[4] = {0.f, 0.f, 0.f, 0.f};
      if (l == 0) {
        const float* Wr = a.dWhh + (size_t)n * H;
#pragma unroll 4
        for (int kk = 0; kk < 512; kk += 4) {
          float4 w4 = *(const float4*)(Wr + kk);
#pragma unroll
          for (int m = 0; m < 4; m++)
            acc[m] += d4(w4, *(const float4*)(Hs + m * 512 + kk));
        }
      } else {
        const float* Wi = a.dWihr + ((size_t)(l - 1) * H + n) * H;
        const float* Wh = a.dWhh + ((size_t)l * H + n) * H;
#pragma unroll 4
        for (int kk = 0; kk < 512; kk += 4) {
          float4 wi4 = *(const float4*)(Wi + kk);
          float4 wh4 = *(const float4*)(Wh + kk);
#pragma unroll
          for (int m = 0; m < 4; m++) {
            acc[m] += d4(wi4, *(const float4*)(Hs + ((l - 1) * 4 + m) * 512 + kk));
            acc[m] += d4(wh4, *(const float4*)(Hs + (l * 4 + m) * 512 + kk));
          }
        }
      }
      float o[4];
#pragma unroll
      for (int m = 0; m < 4; m++) {
        float pre = acc[m] + biasl[l];
        if (l == 0)
          pre += XIN[m * 4 + 0] * wxd0 + XIN[m * 4 + 1] * wxd1 + XIN[m * 4 + 2] * wxd2;
        o[m] = tanhf(pre);
      }
      __syncthreads();   // all reads of Hs[l] complete
#pragma unroll
      for (int m = 0; m < 4; m++) Hs[(l * 4 + m) * 512 + n] = o[m];
      __syncthreads();
    }
    // head: o0 = linW . h3 + lb; xin recurrence; out[b][s]
    {
      int m = tid >> 7, i = tid & 127;
      float4 h4 = *(const float4*)(Hs + (3 * 4 + m) * 512 + i * 4);
      P2[m * 136 + i] = d4(h4, lw);
      __syncthreads();
      if (tid < 128) {
        int mm = tid >> 5, ii = tid & 31;
        float s4 = P2[mm * 136 + ii] + P2[mm * 136 + ii + 32]
                 + P2[mm * 136 + ii + 64] + P2[mm * 136 + ii + 96];
        P2[mm * 136 + ii] = s4;
      }
      __syncthreads();
      if (tid < 4) {
        float sum = 0.f;
        for (int ii = 0; ii < 32; ii++) sum += P2[tid * 136 + ii];
        float o0 = sum + lb;
        float s1v = XIN[tid * 4 + 0] - o0;
        float s2v = XIN[tid * 4 + 1] - s1v;
        XIN[tid * 4 + 0] = o0; XIN[tid * 4 + 1] = s1v; XIN[tid * 4 + 2] = s2v;
        a.out[(size_t)(b0 + tid) * TGT + s] = o0;
      }
      __syncthreads();
    }
  }
}

// ===========================================================================
__global__ __launch_bounds__(512, 1) void birnn_all(Args a) {
  __shared__ __align__(16) float sm[16576];   // 66.3 KB
  const int tid = threadIdx.x, bx = blockIdx.x;
  enc_phase<true>(a, sm, bx, tid);     // E0: 64 blocks active
  gridbar(a.ctr, 128u);
  proj_phase(a, sm, bx, tid);          // all 128 blocks
  gridbar(a.ctr, 256u);
  enc_phase<false>(a, sm, bx, tid);    // E1: 64 blocks active
  gridbar(a.ctr, 384u);
  dec_phase(a, sm, bx, tid);           // 32 blocks active
}

// ---------------------------------------------------------------------------
extern "C" void kernel_launch(void* const* d_in, const int* in_sizes, int n_in,
                              void* d_out, int out_size, void* d_ws, size_t ws_size,
                              hipStream_t stream) {
  float* dst = (float*)d_ws;                                   // 1 MB
  unsigned* ctr = (unsigned*)((char*)d_ws + 1048576);          // 16 KB
  float* l0 = (float*)((char*)d_ws + 1048576 + 16384);         // 64 MB

  kinit<<<16, 256, 0, stream>>>(ctr);

  Args args;
  args.x = (const float*)d_in[0];
  args.eWih0 = (const float*)d_in[2];
  args.eWhh0 = (const float*)d_in[3];
  args.eWih1 = (const float*)d_in[4];
  args.eWhh1 = (const float*)d_in[5];
  args.ebih = (const float*)d_in[6];
  args.ebhh = (const float*)d_in[7];
  args.dWih0 = (const float*)d_in[8];
  args.dWihr = (const float*)d_in[9];
  args.dWhh = (const float*)d_in[10];
  args.dbih = (const float*)d_in[11];
  args.dbhh = (const float*)d_in[12];
  args.linW = (const float*)d_in[13];
  args.linb = (const float*)d_in[14];
  args.dst = dst; args.l0 = l0; args.ctr = ctr;
  args.out = (float*)d_out;

  void* kp[] = { &args };
  hipError_t err = hipLaunchCooperativeKernel((void*)birnn_all, dim3(128), dim3(512),
                                              kp, 0, stream);
  if (err != hipSuccess) {
    // 128 blocks x 8 waves always co-resident on 256 CUs (<= capacity), and
    // phases have no inter-block data deps besides the 3 barriers.
    birnn_all<<<dim3(128), dim3(512), 0, stream>>>(args);
  }
}